// Round 2
// 581.327 us; speedup vs baseline: 1.0880x; 1.0880x over previous
//
#include <hip/hip_runtime.h>

#define HH  512
#define WW  512
#define HPP 64
#define WPP 2048
#define BB  4
#define CC  64

// Fill the center "drop" disk (pixels the scatter never writes) from ref_feat.
// Analytic recomputation of index_y <= 0, with +1e-3 margin: pixels in the
// margin band are also written by sample_scatter, which runs AFTER this kernel
// on the same stream, so any overlap is overwritten with the correct value.
// The disk (depth <= ~16.22px around center 255.5) fits in rows/cols 240..271.
__global__ __launch_bounds__(256) void fill_disk(
    const float* __restrict__ ref, float* __restrict__ out) {
    int t  = blockIdx.x * 256 + threadIdx.x;   // 0..1023 -> 32x32 box
    int bc = blockIdx.y;                       // 0..255 = b*C+c plane
    int r = 240 + (t >> 5);
    int c = 240 + (t & 31);
    float yyc = (float)r - 255.5f;
    float xxc = (float)c - 255.5f;
    float depth = sqrtf(yyc * yyc + xxc * xxc);
    // numpy: index_y = depth / (256*sqrt(2)) * 67 - 3
    float iyv = depth * (67.0f / 362.03867196751236f) - 3.0f;
    if (iyv <= 1e-3f) {
        size_t off = (size_t)bc * (HH * WW) + (size_t)r * WW + c;
        out[off] = ref[off];
    }
}

// 8-byte, 4-aligned pair load (x0 and x0+1 taps in one VMEM op where the
// backend supports unaligned dwordx2; otherwise two dwords — still correct).
struct __attribute__((packed, aligned(4))) fpair { float lo, hi; };

// Bilinear sample (align_corners=True, zero padding) + scatter.
// One thread per masked pixel n for one batch b; loops all 64 channels.
//
// v2 changes vs baseline (263us, 2.0 TB/s, VALUBusy 9% -> VMEM
// transaction/L2-miss bound, not BW-bound):
//  (1) x0/x1 taps fused into ONE 8-byte load per polar row. For this grid
//      ixf is strictly in (0, 2047), so x0 in [0,2046] and x1=x0+1<=2047:
//      an 8B load at (y, x0) always covers both taps in-bounds. Halves the
//      scattered-load instruction count (256 -> 128 per thread).
//  (2) Per-channel addressing is a uniform base advance; the per-lane
//      32-bit offsets (offA/offB) stay fixed.
//  (3) Bijective XCD swizzle of blockIdx.x (nwg=1021 is not %8==0, so use the
//      q/r split form): n-contiguous blocks share one XCD's L2, so each polar
//      cache line is missed into ~1 L2 instead of ~8 -> less L2-miss latency
//      and lower HBM re-fetch (FETCH_SIZE was 1.85x the 128MB polar input).
//
// Writes are coalesced (consecutive n = row-major-consecutive cart pixels);
// nontemporal stores keep the 256MB write stream from thrashing L2/L3 so
// polar lines stay resident for cross-pixel reuse.
__global__ __launch_bounds__(256) void sample_scatter(
    const float* __restrict__ polar,
    const float* __restrict__ gx, const float* __restrict__ gy,
    const int* __restrict__ idx_y, const int* __restrict__ idx_x,
    float* __restrict__ out, int N) {
    // --- bijective XCD swizzle (8 XCDs, round-robin dispatch assumed) ---
    int nwg = gridDim.x;
    int bid = blockIdx.x;
    int q = nwg >> 3, r = nwg & 7;
    int xcd = bid & 7, lid = bid >> 3;
    int swz = (xcd < r ? xcd * (q + 1) : r * (q + 1) + (xcd - r) * q) + lid;

    int n = swz * 256 + (int)threadIdx.x;
    if (n >= N) return;
    int b = blockIdx.y;

    float gxv = gx[n], gyv = gy[n];
    float ixf = (gxv + 1.0f) * ((WPP - 1) * 0.5f);
    float iyf = (gyv + 1.0f) * ((HPP - 1) * 0.5f);
    float x0f = floorf(ixf), y0f = floorf(iyf);
    float wx1 = ixf - x0f,  wy1 = iyf - y0f;
    float wx0 = 1.0f - wx1, wy0 = 1.0f - wy1;
    int x0 = (int)x0f, y0 = (int)y0f;
    int x1 = x0 + 1,   y1 = y0 + 1;

    // Validity zeroing (all true for this grid; kept for safety).
    bool vx0 = (x0 >= 0) & (x0 < WPP);
    bool vx1 = (x1 >= 0) & (x1 < WPP);
    bool vy0 = (y0 >= 0) & (y0 < HPP);
    bool vy1 = (y1 >= 0) & (y1 < HPP);
    float w00 = (vx0 && vy0) ? wx0 * wy0 : 0.0f;
    float w01 = (vx1 && vy0) ? wx1 * wy0 : 0.0f;
    float w10 = (vx0 && vy1) ? wx0 * wy1 : 0.0f;
    float w11 = (vx1 && vy1) ? wx1 * wy1 : 0.0f;

    // Clamped tap coordinates (no-ops in practice: x0 in [0,2046], y0 in [0,62]).
    int xs  = min(max(x0, 0), WPP - 2);
    int ys0 = min(max(y0, 0), HPP - 1);
    int ys1 = min(max(y1, 0), HPP - 1);

    int oy = idx_y[n], ox = idx_x[n];

    const char* pb = (const char*)polar + (size_t)b * ((size_t)CC * HPP * WPP * 4);
    char*       ob = (char*)out + (size_t)b * ((size_t)CC * HH * WW * 4)
                               + (size_t)(oy * WW + ox) * 4;
    unsigned offA = (unsigned)(ys0 * WPP + xs) * 4u;
    unsigned offB = (unsigned)(ys1 * WPP + xs) * 4u;

    #pragma unroll 8
    for (int c = 0; c < CC; ++c) {
        fpair a01 = *(const fpair*)(pb + offA);  // row y0: taps x0, x0+1
        fpair b01 = *(const fpair*)(pb + offB);  // row y1: taps x0, x0+1
        float v = a01.lo * w00 + a01.hi * w01 + b01.lo * w10 + b01.hi * w11;
        __builtin_nontemporal_store(v, (float*)ob);
        pb += (size_t)HPP * WPP * 4;
        ob += (size_t)HH * WW * 4;
    }
}

extern "C" void kernel_launch(void* const* d_in, const int* in_sizes, int n_in,
                              void* d_out, int out_size, void* d_ws, size_t ws_size,
                              hipStream_t stream) {
    const float* polar = (const float*)d_in[0];
    const float* ref   = (const float*)d_in[1];
    const float* gxp   = (const float*)d_in[2];
    const float* gyp   = (const float*)d_in[3];
    const int*   iyp   = (const int*)d_in[4];
    const int*   ixp   = (const int*)d_in[5];
    float* out = (float*)d_out;
    int N = in_sizes[2];

    fill_disk<<<dim3(4, BB * CC), 256, 0, stream>>>(ref, out);
    sample_scatter<<<dim3((N + 255) / 256, BB), 256, 0, stream>>>(
        polar, gxp, gyp, iyp, ixp, out, N);
}